// Round 4
// baseline (110.071 us; speedup 1.0000x reference)
//
#include <hip/hip_runtime.h>
#include <math.h>

#define DIAG 725
#define HALF 362.0f
#define NIMG 512
#define POFF 106          // data block offset inside padded image
#define PS   736          // padded row stride in floats (64B-aligned rows)
#define PI_F 3.14159265358979323846f

// Build padded image AND its transpose (both 725 rows, stride 736, zeros
// everywhere outside the central 512x512 data block).
__global__ __launch_bounds__(256) void pad_kernel(const float* __restrict__ img,
                                                  float* __restrict__ pad,
                                                  float* __restrict__ padT)
{
    const int col = blockIdx.x * 256 + threadIdx.x;   // 0..767 (grid.x = 3)
    const int row = blockIdx.y;                        // 0..724
    if (col >= PS) return;
    float v = 0.0f;
    const int dr = row - POFF, dc = col - POFF;
    if ((unsigned)dr < (unsigned)NIMG && (unsigned)dc < (unsigned)NIMG)
        v = img[dr * NIMG + dc];
    pad[row * PS + col] = v;
    if (col < DIAG && padT)
        padT[col * PS + row] = v;
}

// Per-angle trig table: {ct, st, 1/ct (0 if tiny), 1/st (0 if tiny)}.
__global__ __launch_bounds__(256) void trig_kernel(const float* __restrict__ angles,
                                                   int n_ang, float4* __restrict__ tbl)
{
    const int a = blockIdx.x * 256 + threadIdx.x;
    if (a >= n_ang) return;
    const float rad = -angles[a] * (PI_F / 180.0f);
    const float ct = cosf(rad), st = sinf(rad);
    const float rct = (fabsf(ct) > 1e-4f) ? 1.0f / ct : 0.0f;
    const float rst = (fabsf(st) > 1e-4f) ? 1.0f / st : 0.0f;
    tbl[a] = make_float4(ct, st, rct, rst);
}

// Check-free bilinear sample (coords proven inside the allocated array).
__device__ inline float sample_nc(const float* __restrict__ p0, float X, float Y)
{
    const float fx = floorf(X), fy = floorf(Y);
    const float ax = X - fx,  ay = Y - fy;
    const int idx = (int)fy * PS + (int)fx;
    const float* p = p0 + idx;
    const float Ia = p[0], Ib = p[1], Ic = p[PS], Id = p[PS + 1];
    const float top = fmaf(ax, Ib - Ia, Ia);
    const float bot = fmaf(ax, Id - Ic, Ic);
    return fmaf(ay, bot - top, top);
}

// One wave per (angle a, sinogram row r); lanes stride c.
// Near-vertical angles sample the transposed image with swapped coords so the
// fast coordinate is always the contiguous one.
__global__ __launch_bounds__(256) void radon_uni(const float* __restrict__ pad,
                                                 const float* __restrict__ padT,
                                                 const float4* __restrict__ tbl,
                                                 float* __restrict__ out, int n_ang)
{
    const int wib = (int)(threadIdx.x >> 6);
    const int lane = (int)(threadIdx.x & 63);
    const int w = (int)blockIdx.x * 4 + wib;
    const int a = w / DIAG;
    const int r = w - a * DIAG;
    if (a >= n_ang) return;

    const float4 t = tbl[a];
    const float ct = t.x, st = t.y, rct = t.z, rst = t.w;

    const float dy = (float)r - HALF;
    const float Bx = HALF - HALF * ct - st * dy;   // x(c) = ct*c + Bx
    const float By = HALF - HALF * st + ct * dy;   // y(c) = st*c + By

    // c-interval where the 2x2 footprint can touch the data block.
    float lo = 0.0f, hi = 724.0f;
    if (rct != 0.0f) {
        const float c1 = (104.0f - Bx) * rct, c2 = (619.0f - Bx) * rct;
        lo = fmaxf(lo, fminf(c1, c2)); hi = fminf(hi, fmaxf(c1, c2));
    } else if (Bx < 103.0f || Bx > 620.0f) { hi = -1.0f; }
    if (rst != 0.0f) {
        const float c1 = (104.0f - By) * rst, c2 = (619.0f - By) * rst;
        lo = fmaxf(lo, fminf(c1, c2)); hi = fminf(hi, fmaxf(c1, c2));
    } else if (By < 103.0f || By > 620.0f) { hi = -1.0f; }

    int nfull = 0, tail = 0, clo = 0, chi = 0;
    if (hi >= lo) {
        clo = (int)fmaxf(0.0f, floorf(lo));
        chi = (int)fminf(724.0f, ceilf(hi));
        const int len = chi - clo + 1;
        if (len > 0) { nfull = len >> 6; tail = len & 63; }
    }

    // Frame select: fast coordinate = larger |step|.
    const bool useT = (fabsf(st) > fabsf(ct)) && (padT != nullptr);
    const float* imgp = useT ? padT : pad;
    const float cF = useT ? st : ct;
    const float cS = useT ? ct : st;
    const float bF = useT ? By : Bx;
    const float bS = useT ? Bx : By;

    float fc = (float)(clo + lane);
    float s0 = 0.0f, s1 = 0.0f;
    int k = 0;
    for (; k + 2 <= nfull; k += 2) {       // check-free main body
        s0 += sample_nc(imgp, fmaf(cF, fc, bF),          fmaf(cS, fc, bS));
        s1 += sample_nc(imgp, fmaf(cF, fc + 64.0f, bF),  fmaf(cS, fc + 64.0f, bS));
        fc += 128.0f;
    }
    if (k < nfull) {
        s0 += sample_nc(imgp, fmaf(cF, fc, bF), fmaf(cS, fc, bS));
        fc += 64.0f;
    }
    if (tail) {                             // masked tail (addresses proven safe)
        const float val = sample_nc(imgp, fmaf(cF, fc, bF), fmaf(cS, fc, bS));
        s1 += (fc <= (float)chi) ? val : 0.0f;
    }

    float sum = s0 + s1;
    #pragma unroll
    for (int off = 32; off > 0; off >>= 1)
        sum += __shfl_down(sum, off);
    if (lane == 0)
        out[r * n_ang + a] = sum;
}

extern "C" void kernel_launch(void* const* d_in, const int* in_sizes, int n_in,
                              void* d_out, int out_size, void* d_ws, size_t ws_size,
                              hipStream_t stream) {
    const float* img = (const float*)d_in[0];
    const float* angles = (const float*)d_in[1];
    float* out = (float*)d_out;
    const int n_ang = in_sizes[1];

    const size_t img_f = (size_t)DIAG * PS;             // 533,600 floats
    float* pad = (float*)d_ws;
    float4* tbl = (float4*)(pad + img_f);
    float* padT_cand = (float*)(tbl + 256);
    const size_t need_full = (img_f * 2 + 256 * 4) * sizeof(float);
    float* padT = (ws_size >= need_full) ? padT_cand : nullptr;

    pad_kernel<<<dim3(3, DIAG), 256, 0, stream>>>(img, pad, padT);
    trig_kernel<<<(n_ang + 255) / 256, 256, 0, stream>>>(angles, n_ang, tbl);

    const int waves = n_ang * DIAG;
    radon_uni<<<(waves + 3) / 4, 256, 0, stream>>>(pad, padT, tbl, out, n_ang);
}